// Round 13
// baseline (590.996 us; speedup 1.0000x reference)
//
#include <hip/hip_runtime.h>
#include <hip/hip_fp16.h>
#include <math.h>

#define NN 50000
#define NE 640000
#define F  32
#define KCH 9
#define CUT 5.0f

#define C13 (1.0f/3.0f)
#define C23 (2.0f/3.0f)
#define C15 0.2f
#define C25 0.4f
#define C17 (1.0f/7.0f)
#define C27 (2.0f/7.0f)
#define IS3 0.5773502691896258f
#define S35 0.3464101615137755f
#define S37 0.2474358296526968f
#define S3  1.7320508075688772f

#define NBLK 2048
#define NHALF (NBLK * 8)

union U2H { unsigned int u; __half2 h; };

__device__ __forceinline__ unsigned int pack2(float a, float b) {
    U2H c; c.h = __floats2half2_rn(a, b); return c.u;
}
__device__ __forceinline__ float2 unpack2(unsigned int u) {
    U2H c; c.u = u; return __half22float2(c.h);
}
__device__ __forceinline__ float h2f(ushort u) {
    return __half2float(__ushort_as_half(u));
}

__global__ __launch_bounds__(256) void init_x(const float* __restrict__ embed,
                                              const int* __restrict__ Z,
                                              float* __restrict__ x0,
                                              ushort* __restrict__ x0h,
                                              uint4* __restrict__ xhA,
                                              ushort* __restrict__ xhB) {
    int idx = blockIdx.x * 256 + threadIdx.x;
    int n = idx >> 5;
    float v = embed[Z[n] * F + (idx & 31)];
    x0[idx] = v;
    unsigned int p = pack2(v, 0.f);
    x0h[idx] = (ushort)(p & 0xFFFFu);
    uint4 ua; ua.x = p; ua.y = 0u; ua.z = 0u; ua.w = 0u;
    xhA[idx] = ua;
    xhB[idx] = 0;
}

__global__ __launch_bounds__(256) void hist_kernel(const int* __restrict__ idx_i,
                                                   const int* __restrict__ idx_j,
                                                   const float* __restrict__ dr,
                                                   int* __restrict__ cnt) {
    int e = blockIdx.x * 256 + threadIdx.x;
    if (e >= NE) return;
    int ni = idx_i[e], nj = idx_j[e];
    float dx = dr[3 * e + 0], dy = dr[3 * e + 1], dz = dr[3 * e + 2];
    float r2 = fmaf(dx, dx, fmaf(dy, dy, dz * dz));
    if (ni != nj && r2 < CUT * CUT) atomicAdd(&cnt[ni], 1);
}

#define SCAN_T 1024
#define SCAN_C ((NN + SCAN_T - 1) / SCAN_T)

__global__ __launch_bounds__(SCAN_T) void scan_kernel(const int* __restrict__ cnt,
                                                      int* __restrict__ offs,
                                                      int* __restrict__ head) {
    __shared__ int ps[SCAN_T];
    int t = threadIdx.x;
    int b = t * SCAN_C;
    int e = min(b + SCAN_C, NN);
    int s = 0;
    for (int i = b; i < e; ++i) s += cnt[i];
    ps[t] = s;
    __syncthreads();
    for (int off = 1; off < SCAN_T; off <<= 1) {
        int v = (t >= off) ? ps[t - off] : 0;
        __syncthreads();
        ps[t] += v;
        __syncthreads();
    }
    int run = (t == 0) ? 0 : ps[t - 1];
    for (int i = b; i < e; ++i) { int c = cnt[i]; offs[i] = run; head[i] = run; run += c; }
    if (t == SCAN_T - 1) offs[NN] = ps[SCAN_T - 1];
}

// zero the 8-entry pads past the live edge count (prefetch safety)
__global__ void pad_zero(const int* __restrict__ neptr,
                         uint4* __restrict__ geoA,
                         uint2* __restrict__ geoB,
                         ushort* __restrict__ njA) {
    int NEl = neptr[0];
    int i = threadIdx.x;
    if (i < 8) {
        uint4 z4; z4.x = z4.y = z4.z = z4.w = 0u;
        uint2 z2; z2.x = z2.y = 0u;
        geoA[NEl + i] = z4;
        geoB[NEl + i] = z2;
        njA[NEl + i] = 0;
    }
}

// geoA[p] = {u_xy(h2), uz(h)|dst<<16, rc01(h2), rc23(h2)}; geoB[p] = {rc45, rc67}; njA[p] = nj
__global__ __launch_bounds__(256) void fill_kernel(const int* __restrict__ idx_i,
                                                   const int* __restrict__ idx_j,
                                                   const float* __restrict__ dr,
                                                   int* __restrict__ head,
                                                   uint4* __restrict__ geoA,
                                                   uint2* __restrict__ geoB,
                                                   ushort* __restrict__ njA) {
    int e = blockIdx.x * 256 + threadIdx.x;
    if (e >= NE) return;
    int ni = idx_i[e], nj = idx_j[e];
    float dx = dr[3 * e + 0], dy = dr[3 * e + 1], dz = dr[3 * e + 2];
    float r2 = fmaf(dx, dx, fmaf(dy, dy, dz * dz));
    if (!(ni != nj && r2 < CUT * CUT)) return;

    float r = sqrtf(r2);
    float inv = 1.0f / fmaxf(r, 1e-9f);
    float ux = dx * inv, uy = dy * inv, uz = dz * inv;

    float cut = expf(-r2 / fmaxf(CUT * CUT - r2, 1e-12f));
    float ur = r / (1.0f + r), vr = 1.0f - ur;
    float up2 = ur*ur, up3 = up2*ur, up4 = up3*ur, up5 = up4*ur, up6 = up5*ur, up7 = up6*ur;
    float vp2 = vr*vr, vp3 = vp2*vr, vp4 = vp3*vr, vp5 = vp4*vr, vp6 = vp5*vr, vp7 = vp6*vr;

    int p = atomicAdd(&head[ni], 1);
    uint4 gA;
    gA.x = pack2(ux, uy);
    gA.y = (pack2(uz, 0.f) & 0xFFFFu) | ((unsigned int)ni << 16);
    gA.z = pack2(cut * vp7,              cut * 7.f  * ur  * vp6);
    gA.w = pack2(cut * 21.f * up2 * vp5, cut * 35.f * up3 * vp4);
    uint2 gB;
    gB.x = pack2(cut * 35.f * up4 * vp3, cut * 21.f * up5 * vp2);
    gB.y = pack2(cut * 7.f  * up6 * vr,  cut * up7);
    geoA[p] = gA;
    geoB[p] = gB;
    njA[p] = (ushort)nj;
}

template<int MODE>
__device__ __forceinline__ void flush_acc(float* __restrict__ m, int cur, int f,
                                          float* __restrict__ acc) {
    if (cur < 0) return;
    if (MODE == 2) {
        unsafeAtomicAdd(m + (size_t)cur * F + f, acc[0]);
    } else {
        float* mp = m + (size_t)cur * KCH * F + f;
        #pragma unroll
        for (int a = 0; a < KCH; ++a) unsafeAtomicAdd(mp + a * F, acc[a]);
    }
}

// Strip-parallel segmented reduction, single-step loop, register-lean (<=64 VGPR target):
// geo read JIT-first; xe prefetch depth-1 with nj address ready 2 iterations early
// (nj ring of 2); prefetches issued last so in-order vmcnt retirement never blocks
// consumables on them.
template<int MODE>   // 0=FIRST(x0h), 1=MID(full Gaunt), 2=LAST(y0 only)
__global__ __launch_bounds__(256) void gather_kernel(const uint4* __restrict__ geoA,
                                                     const uint2* __restrict__ geoB,
                                                     const ushort* __restrict__ njA,
                                                     const ushort* __restrict__ x0h,
                                                     const uint4* __restrict__ xhA,
                                                     const ushort* __restrict__ xhB,
                                                     const float* __restrict__ rw_iter,
                                                     const int* __restrict__ neptr,
                                                     float* __restrict__ m) {
    int lane = threadIdx.x & 63;
    int wid  = threadIdx.x >> 6;
    int half = lane >> 5;
    int f    = lane & 31;
    int lb   = (blockIdx.x & 7) * (NBLK / 8) + (blockIdx.x >> 3);  // XCD-chunked
    int h    = lb * 8 + wid * 2 + half;

    float rwv[24];
    #pragma unroll
    for (int q = 0; q < 24; ++q) rwv[q] = rw_iter[q * F + f];
    if (MODE == 2) {
        #pragma unroll
        for (int q = 8; q < 16; ++q) rwv[q] *= C13;
        #pragma unroll
        for (int q = 16; q < 24; ++q) rwv[q] *= C15;
    }

    int NEl = neptr[0];
    int per = (NEl + NHALF - 1) / NHALF;
    int s = h * per;
    int e = min(s + per, NEl);
    if (s >= e) return;

    constexpr int NACC = (MODE == 2) ? 1 : KCH;
    float acc[NACC];
    #pragma unroll
    for (int a = 0; a < NACC; ++a) acc[a] = 0.f;
    int cur = -1;

    // prologue: blocking loads once per strip
    int nj1 = (int)njA[s + 1];     // for edge s+1 (pad-safe)
    int nj2 = (int)njA[s + 2];     // for edge s+2 (pad-safe)
    uint4 xa_c = {};
    ushort x8_c;
    {
        int nj_c = (int)njA[s];
        if (MODE == 0) {
            x8_c = x0h[nj_c * F + f];
        } else {
            xa_c = xhA[nj_c * F + f];
            x8_c = xhB[nj_c * F + f];
        }
    }

    for (int t = s; t < e; ++t) {
        // --- JIT consumables first (retire before younger prefetches) ---
        uint4 gA = geoA[t];
        uint2 gB = geoB[t];

        // --- prefetches last: xe for edge t+1 (address nj1 ready 2 iters), nj stream ---
        uint4 xa_n = {};
        ushort x8_n;
        if (MODE == 0) {
            x8_n = x0h[nj1 * F + f];
        } else {
            xa_n = xhA[nj1 * F + f];
            x8_n = xhB[nj1 * F + f];
        }
        int njt = (int)njA[t + 3];   // pad-safe

        // --- segment flush on destination change ---
        int dst = (int)(gA.y >> 16);
        if (dst != cur) {
            flush_acc<MODE>(m, cur, f, acc);
            cur = dst;
            #pragma unroll
            for (int a = 0; a < NACC; ++a) acc[a] = 0.f;
        }

        // --- compute edge t ---
        float2 uxy = unpack2(gA.x);
        float ux = uxy.x, uy = uxy.y;
        float uz = h2f((ushort)(gA.y & 0xFFFFu));
        float2 rcA = unpack2(gA.z);
        float2 rcB = unpack2(gA.w);
        float2 rcC = unpack2(gB.x);
        float2 rcD = unpack2(gB.y);

        float g0, g1, g2;
        g0 = rcA.x * rwv[0];
        g0 = fmaf(rcA.y, rwv[1], g0); g0 = fmaf(rcB.x, rwv[2], g0); g0 = fmaf(rcB.y, rwv[3], g0);
        g0 = fmaf(rcC.x, rwv[4], g0); g0 = fmaf(rcC.y, rwv[5], g0); g0 = fmaf(rcD.x, rwv[6], g0);
        g0 = fmaf(rcD.y, rwv[7], g0);
        g1 = rcA.x * rwv[8];
        g1 = fmaf(rcA.y, rwv[9],  g1); g1 = fmaf(rcB.x, rwv[10], g1); g1 = fmaf(rcB.y, rwv[11], g1);
        g1 = fmaf(rcC.x, rwv[12], g1); g1 = fmaf(rcC.y, rwv[13], g1); g1 = fmaf(rcD.x, rwv[14], g1);
        g1 = fmaf(rcD.y, rwv[15], g1);
        g2 = rcA.x * rwv[16];
        g2 = fmaf(rcA.y, rwv[17], g2); g2 = fmaf(rcB.x, rwv[18], g2); g2 = fmaf(rcB.y, rwv[19], g2);
        g2 = fmaf(rcC.x, rwv[20], g2); g2 = fmaf(rcC.y, rwv[21], g2); g2 = fmaf(rcD.x, rwv[22], g2);
        g2 = fmaf(rcD.y, rwv[23], g2);

        if (MODE == 0) {
            float xe0 = h2f(x8_c);
            float s2 = S3 * g2;
            acc[0] = fmaf(xe0, g0, acc[0]);
            acc[1] = fmaf(xe0, uy * g1, acc[1]);
            acc[2] = fmaf(xe0, uz * g1, acc[2]);
            acc[3] = fmaf(xe0, ux * g1, acc[3]);
            acc[4] = fmaf(xe0, s2 * ux * uy, acc[4]);
            acc[5] = fmaf(xe0, s2 * uy * uz, acc[5]);
            acc[6] = fmaf(xe0, fmaf(1.5f * uz, uz, -0.5f) * g2, acc[6]);
            acc[7] = fmaf(xe0, s2 * ux * uz, acc[7]);
            acc[8] = fmaf(xe0, 0.5f * s2 * (ux * ux - uy * uy), acc[8]);
        } else {
            float xe[9];
            {
                float2 p;
                p = unpack2(xa_c.x); xe[0] = p.x; xe[1] = p.y;
                p = unpack2(xa_c.y); xe[2] = p.x; xe[3] = p.y;
                p = unpack2(xa_c.z); xe[4] = p.x; xe[5] = p.y;
                p = unpack2(xa_c.w); xe[6] = p.x; xe[7] = p.y;
                xe[8] = h2f(x8_c);
            }
            if (MODE == 2) {
                float dot1 = uy * xe[1];
                dot1 = fmaf(uz, xe[2], dot1);
                dot1 = fmaf(ux, xe[3], dot1);
                float Y4 = S3 * ux * uy, Y5 = S3 * uy * uz, Y7 = S3 * ux * uz;
                float Y6 = fmaf(1.5f * uz, uz, -0.5f);
                float Y8 = 0.5f * S3 * (ux * ux - uy * uy);
                float dot2 = Y4 * xe[4];
                dot2 = fmaf(Y5, xe[5], dot2);
                dot2 = fmaf(Y6, xe[6], dot2);
                dot2 = fmaf(Y7, xe[7], dot2);
                dot2 = fmaf(Y8, xe[8], dot2);
                acc[0] = fmaf(g0, xe[0], acc[0]);
                acc[0] = fmaf(g1, dot1, acc[0]);
                acc[0] = fmaf(g2, dot2, acc[0]);
            } else {
                float s2 = S3 * g2;
                float w[9];
                w[0] = g0;
                w[1] = uy * g1; w[2] = uz * g1; w[3] = ux * g1;
                w[4] = s2 * ux * uy;
                w[5] = s2 * uy * uz;
                w[6] = fmaf(1.5f * uz, uz, -0.5f) * g2;
                w[7] = s2 * ux * uz;
                w[8] = 0.5f * s2 * (ux * ux - uy * uy);

                float d0v = xe[0]*w[0], d1v = xe[1]*w[1], d2v = xe[2]*w[2], d3v = xe[3]*w[3];
                float d4v = xe[4]*w[4], d5v = xe[5]*w[5], d6v = xe[6]*w[6], d7v = xe[7]*w[7];
                float d8v = xe[8]*w[8];

                acc[0] += d0v + C13 * (d1v + d2v + d3v) + C15 * (d4v + d5v + d6v + d7v + d8v);
                #define T(a, b) (xe[a] * w[b] + xe[b] * w[a])
                acc[1] += T(0,1) - C15 * T(1,6) - S35 * T(1,8) + S35 * T(2,5) + S35 * T(3,4);
                acc[2] += T(0,2) + S35 * T(1,5) + C25 * T(2,6) + S35 * T(3,7);
                acc[3] += T(0,3) + S35 * T(1,4) + S35 * T(2,7) - C15 * T(3,6) + S35 * T(3,8);
                acc[4] += T(0,4) + IS3 * T(1,3) - C27 * T(4,6) + S37 * T(5,7);
                acc[5] += T(0,5) + IS3 * T(1,2) + S37 * T(4,7) + C17 * T(5,6) - S37 * T(5,8);
                acc[6] += T(0,6) - C13 * d1v + C23 * d2v - C13 * d3v
                        - C27 * d4v + C17 * d5v + C27 * d6v + C17 * d7v - C27 * d8v;
                acc[7] += T(0,7) + IS3 * T(2,3) + S37 * T(4,5) + C17 * T(6,7) + S37 * T(7,8);
                acc[8] += T(0,8) - IS3 * d1v + IS3 * d3v - S37 * d5v + S37 * d7v - C27 * T(6,8);
                #undef T
            }
        }

        // rotate
        xa_c = xa_n; x8_c = x8_n;
        nj1 = nj2; nj2 = njt;
    }
    flush_acc<MODE>(m, cur, f, acc);
}

// thread = (node, f). State in fp16 (xhA/xhB) + f32 master of k=0 row (x0).
__global__ __launch_bounds__(256) void node_full(float* __restrict__ x0,
                                                 const float* __restrict__ m,
                                                 uint4* __restrict__ xhA,
                                                 ushort* __restrict__ xhB,
                                                 const float* __restrict__ w1,
                                                 const float* __restrict__ b1,
                                                 const float* __restrict__ w2,
                                                 const float* __restrict__ b2) {
    __shared__ float tile[8][KCH][F];
    int nl = threadIdx.x >> 5, f = threadIdx.x & 31;
    int n = blockIdx.x * 8 + nl;

    float w1c[F];
    #pragma unroll
    for (int fi = 0; fi < F; ++fi) w1c[fi] = w1[fi * F + f];

    float xk[KCH];
    {
        uint4 ua = xhA[n * F + f];
        ushort ub = xhB[n * F + f];
        float2 p;
        p = unpack2(ua.x); xk[0] = p.x; xk[1] = p.y;
        p = unpack2(ua.y); xk[2] = p.x; xk[3] = p.y;
        p = unpack2(ua.z); xk[4] = p.x; xk[5] = p.y;
        p = unpack2(ua.w); xk[6] = p.x; xk[7] = p.y;
        xk[8] = h2f(ub);
    }
    xk[0] = x0[n * F + f];

    #pragma unroll
    for (int k = 0; k < KCH; ++k)
        tile[nl][k][f] = xk[k] + m[((size_t)n * KCH + k) * F + f];
    __syncthreads();

    float o1[KCH];
    #pragma unroll
    for (int k = 0; k < KCH; ++k) {
        float s = 0.f;
        #pragma unroll
        for (int fi = 0; fi < F; ++fi) s = fmaf(tile[nl][k][fi], w1c[fi], s);
        o1[k] = s;
    }
    o1[0] += b1[f];
    float gate = 1.0f / (1.0f + expf(-o1[0]));
    __syncthreads();
    #pragma unroll
    for (int k = 0; k < KCH; ++k) tile[nl][k][f] = o1[k] * gate;
    __syncthreads();

    float w2c[F];
    #pragma unroll
    for (int fi = 0; fi < F; ++fi) w2c[fi] = w2[fi * F + f];

    float xn[KCH];
    #pragma unroll
    for (int k = 0; k < KCH; ++k) {
        float s = (k == 0) ? b2[f] : 0.f;
        #pragma unroll
        for (int fi = 0; fi < F; ++fi) s = fmaf(tile[nl][k][fi], w2c[fi], s);
        xn[k] = xk[k] + s;
    }

    x0[n * F + f] = xn[0];
    uint4 ua;
    ua.x = pack2(xn[0], xn[1]); ua.y = pack2(xn[2], xn[3]);
    ua.z = pack2(xn[4], xn[5]); ua.w = pack2(xn[6], xn[7]);
    xhA[n * F + f] = ua;
    xhB[n * F + f] = __half_as_ushort(__float2half_rn(xn[8]));
}

__global__ __launch_bounds__(256) void node_last(const float* __restrict__ x0,
                                                 const float* __restrict__ m1,
                                                 const float* __restrict__ w1,
                                                 const float* __restrict__ b1,
                                                 const float* __restrict__ w2,
                                                 const float* __restrict__ b2,
                                                 float* __restrict__ out) {
    __shared__ float tile[8][F];
    int nl = threadIdx.x >> 5, f = threadIdx.x & 31;
    int n = blockIdx.x * 8 + nl;

    float w1c[F];
    #pragma unroll
    for (int fi = 0; fi < F; ++fi) w1c[fi] = w1[fi * F + f];

    float xv = x0[n * F + f];
    tile[nl][f] = xv + m1[(size_t)n * F + f];
    __syncthreads();
    float s = 0.f;
    #pragma unroll
    for (int fi = 0; fi < F; ++fi) s = fmaf(tile[nl][fi], w1c[fi], s);
    s += b1[f];
    float gate = 1.0f / (1.0f + expf(-s));
    float h2v = s * gate;
    __syncthreads();
    tile[nl][f] = h2v;
    __syncthreads();
    float w2c[F];
    #pragma unroll
    for (int fi = 0; fi < F; ++fi) w2c[fi] = w2[fi * F + f];
    float o = b2[f];
    #pragma unroll
    for (int fi = 0; fi < F; ++fi) o = fmaf(tile[nl][fi], w2c[fi], o);
    out[(size_t)n * F + f] = xv + o;
}

extern "C" void kernel_launch(void* const* d_in, const int* in_sizes, int n_in,
                              void* d_out, int out_size, void* d_ws, size_t ws_size,
                              hipStream_t stream) {
    (void)in_sizes; (void)n_in; (void)out_size; (void)ws_size;
    const float* dr    = (const float*)d_in[0];
    const float* embed = (const float*)d_in[1];
    const float* rad_w = (const float*)d_in[2];
    const float* d1w   = (const float*)d_in[3];
    const float* d1b   = (const float*)d_in[4];
    const float* d2w   = (const float*)d_in[5];
    const float* d2b   = (const float*)d_in[6];
    const int*   Z     = (const int*)d_in[7];
    const int*   nidx  = (const int*)d_in[8];
    const int* idx_i = nidx;
    const int* idx_j = nidx + NE;

    // workspace layout (16B-aligned head); geo/nj streams padded by 8 entries
    uint4* xhA  = (uint4*)d_ws;                                 // NN*F uint4
    float* m    = (float*)(xhA + (size_t)NN * F);               // NN*9*F f32
    float* x0   = m + (size_t)NN * KCH * F;                     // NN*F f32
    ushort* x0h = (ushort*)(x0 + (size_t)NN * F);               // NN*F u16
    ushort* xhB = x0h + (size_t)NN * F;                         // NN*F u16
    uint4* geoA = (uint4*)(xhB + (size_t)NN * F);               // (NE+8) uint4
    uint2* geoB = (uint2*)(geoA + (size_t)NE + 8);              // (NE+8) uint2
    ushort* njA = (ushort*)(geoB + (size_t)NE + 8);             // (NE+8) u16
    int* offs = (int*)(njA + (size_t)NE + 8);                   // NN+1
    int* head = offs + (NN + 1);
    int* cnt  = head + NN;
    float* outp = (float*)d_out;

    size_t MB_full = (size_t)NN * KCH * F * sizeof(float);
    size_t MB_last = (size_t)NN * F * sizeof(float);

    hipMemsetAsync(cnt, 0, NN * sizeof(int), stream);
    hist_kernel<<<(NE + 255) / 256, 256, 0, stream>>>(idx_i, idx_j, dr, cnt);
    scan_kernel<<<1, SCAN_T, 0, stream>>>(cnt, offs, head);
    pad_zero<<<1, 64, 0, stream>>>(offs + NN, geoA, geoB, njA);
    fill_kernel<<<(NE + 255) / 256, 256, 0, stream>>>(idx_i, idx_j, dr, head, geoA, geoB, njA);

    init_x<<<NN * F / 256, 256, 0, stream>>>(embed, Z, x0, x0h, xhA, xhB);

    const int* neptr = offs + NN;
    for (int i = 0; i < 3; ++i) {
        const float* rwi = rad_w + (size_t)i * 3 * 8 * F;
        const float* w1 = d1w + (size_t)i * F * F;
        const float* b1 = d1b + (size_t)i * F;
        const float* w2 = d2w + (size_t)i * F * F;
        const float* b2 = d2b + (size_t)i * F;
        if (i == 0) {
            hipMemsetAsync(m, 0, MB_full, stream);
            gather_kernel<0><<<NBLK, 256, 0, stream>>>(geoA, geoB, njA, x0h, xhA, xhB, rwi, neptr, m);
            node_full<<<NN / 8, 256, 0, stream>>>(x0, m, xhA, xhB, w1, b1, w2, b2);
        } else if (i == 1) {
            hipMemsetAsync(m, 0, MB_full, stream);
            gather_kernel<1><<<NBLK, 256, 0, stream>>>(geoA, geoB, njA, x0h, xhA, xhB, rwi, neptr, m);
            node_full<<<NN / 8, 256, 0, stream>>>(x0, m, xhA, xhB, w1, b1, w2, b2);
        } else {
            hipMemsetAsync(m, 0, MB_last, stream);
            gather_kernel<2><<<NBLK, 256, 0, stream>>>(geoA, geoB, njA, x0h, xhA, xhB, rwi, neptr, m);
            node_last<<<NN / 8, 256, 0, stream>>>(x0, m, w1, b1, w2, b2, outp);
        }
    }
}

// Round 14
// 570.994 us; speedup vs baseline: 1.0350x; 1.0350x over previous
//
#include <hip/hip_runtime.h>
#include <hip/hip_fp16.h>
#include <math.h>

#define NN 50000
#define NE 640000
#define F  32
#define KCH 9
#define CUT 5.0f

#define C13 (1.0f/3.0f)
#define C23 (2.0f/3.0f)
#define C15 0.2f
#define C25 0.4f
#define C17 (1.0f/7.0f)
#define C27 (2.0f/7.0f)
#define IS3 0.5773502691896258f
#define S35 0.3464101615137755f
#define S37 0.2474358296526968f
#define S3  1.7320508075688772f

#define NBLK 2048
#define NHALF (NBLK * 8)

typedef _Float16 h2 __attribute__((ext_vector_type(2)));

union U2H { unsigned int u; __half2 h; };
union UH2 { unsigned int u; h2 v; };

__device__ __forceinline__ unsigned int pack2(float a, float b) {
    U2H c; c.h = __floats2half2_rn(a, b); return c.u;
}
__device__ __forceinline__ float2 unpack2(unsigned int u) {
    U2H c; c.u = u; return __half22float2(c.h);
}
__device__ __forceinline__ float h2f(ushort u) {
    return __half2float(__ushort_as_half(u));
}
__device__ __forceinline__ h2 as_h2(unsigned int u) { UH2 c; c.u = u; return c.v; }

__device__ __forceinline__ float fdot2f(h2 a, h2 b, float c) {
#if __has_builtin(__builtin_amdgcn_fdot2)
    return __builtin_amdgcn_fdot2(a, b, c, false);
#else
    return fmaf((float)a.x, (float)b.x, fmaf((float)a.y, (float)b.y, c));
#endif
}

__global__ __launch_bounds__(256) void init_x(const float* __restrict__ embed,
                                              const int* __restrict__ Z,
                                              float* __restrict__ x0,
                                              ushort* __restrict__ x0h,
                                              uint4* __restrict__ xhA,
                                              ushort* __restrict__ xhB) {
    int idx = blockIdx.x * 256 + threadIdx.x;
    int n = idx >> 5;
    float v = embed[Z[n] * F + (idx & 31)];
    x0[idx] = v;
    unsigned int p = pack2(v, 0.f);
    x0h[idx] = (ushort)(p & 0xFFFFu);
    uint4 ua; ua.x = p; ua.y = 0u; ua.z = 0u; ua.w = 0u;
    xhA[idx] = ua;
    xhB[idx] = 0;
}

__global__ __launch_bounds__(256) void hist_kernel(const int* __restrict__ idx_i,
                                                   const int* __restrict__ idx_j,
                                                   const float* __restrict__ dr,
                                                   int* __restrict__ cnt) {
    int e = blockIdx.x * 256 + threadIdx.x;
    if (e >= NE) return;
    int ni = idx_i[e], nj = idx_j[e];
    float dx = dr[3 * e + 0], dy = dr[3 * e + 1], dz = dr[3 * e + 2];
    float r2 = fmaf(dx, dx, fmaf(dy, dy, dz * dz));
    if (ni != nj && r2 < CUT * CUT) atomicAdd(&cnt[ni], 1);
}

#define SCAN_T 1024
#define SCAN_C ((NN + SCAN_T - 1) / SCAN_T)

__global__ __launch_bounds__(SCAN_T) void scan_kernel(const int* __restrict__ cnt,
                                                      int* __restrict__ offs,
                                                      int* __restrict__ head) {
    __shared__ int ps[SCAN_T];
    int t = threadIdx.x;
    int b = t * SCAN_C;
    int e = min(b + SCAN_C, NN);
    int s = 0;
    for (int i = b; i < e; ++i) s += cnt[i];
    ps[t] = s;
    __syncthreads();
    for (int off = 1; off < SCAN_T; off <<= 1) {
        int v = (t >= off) ? ps[t - off] : 0;
        __syncthreads();
        ps[t] += v;
        __syncthreads();
    }
    int run = (t == 0) ? 0 : ps[t - 1];
    for (int i = b; i < e; ++i) { int c = cnt[i]; offs[i] = run; head[i] = run; run += c; }
    if (t == SCAN_T - 1) offs[NN] = ps[SCAN_T - 1];
}

// zero the 8-entry pads past the live edge count (prefetch safety)
__global__ void pad_zero(const int* __restrict__ neptr,
                         uint4* __restrict__ geoA,
                         uint2* __restrict__ geoB,
                         ushort* __restrict__ njA) {
    int NEl = neptr[0];
    int i = threadIdx.x;   // 8 threads
    if (i < 8) {
        uint4 z4; z4.x = z4.y = z4.z = z4.w = 0u;
        uint2 z2; z2.x = z2.y = 0u;
        geoA[NEl + i] = z4;
        geoB[NEl + i] = z2;
        njA[NEl + i] = 0;
    }
}

// geoA[p] = {u_xy(h2), uz(h)|dst<<16, rc01(h2), rc23(h2)}; geoB[p] = {rc45, rc67}; njA[p] = nj
__global__ __launch_bounds__(256) void fill_kernel(const int* __restrict__ idx_i,
                                                   const int* __restrict__ idx_j,
                                                   const float* __restrict__ dr,
                                                   int* __restrict__ head,
                                                   uint4* __restrict__ geoA,
                                                   uint2* __restrict__ geoB,
                                                   ushort* __restrict__ njA) {
    int e = blockIdx.x * 256 + threadIdx.x;
    if (e >= NE) return;
    int ni = idx_i[e], nj = idx_j[e];
    float dx = dr[3 * e + 0], dy = dr[3 * e + 1], dz = dr[3 * e + 2];
    float r2 = fmaf(dx, dx, fmaf(dy, dy, dz * dz));
    if (!(ni != nj && r2 < CUT * CUT)) return;

    float r = sqrtf(r2);
    float inv = 1.0f / fmaxf(r, 1e-9f);
    float ux = dx * inv, uy = dy * inv, uz = dz * inv;

    float cut = expf(-r2 / fmaxf(CUT * CUT - r2, 1e-12f));
    float ur = r / (1.0f + r), vr = 1.0f - ur;
    float up2 = ur*ur, up3 = up2*ur, up4 = up3*ur, up5 = up4*ur, up6 = up5*ur, up7 = up6*ur;
    float vp2 = vr*vr, vp3 = vp2*vr, vp4 = vp3*vr, vp5 = vp4*vr, vp6 = vp5*vr, vp7 = vp6*vr;

    int p = atomicAdd(&head[ni], 1);
    uint4 gA;
    gA.x = pack2(ux, uy);
    gA.y = (pack2(uz, 0.f) & 0xFFFFu) | ((unsigned int)ni << 16);
    gA.z = pack2(cut * vp7,              cut * 7.f  * ur  * vp6);
    gA.w = pack2(cut * 21.f * up2 * vp5, cut * 35.f * up3 * vp4);
    uint2 gB;
    gB.x = pack2(cut * 35.f * up4 * vp3, cut * 21.f * up5 * vp2);
    gB.y = pack2(cut * 7.f  * up6 * vr,  cut * up7);
    geoA[p] = gA;
    geoB[p] = gB;
    njA[p] = (ushort)nj;
}

template<int MODE>
__device__ __forceinline__ void flush_acc(float* __restrict__ m, int cur, int f,
                                          float* __restrict__ acc) {
    if (cur < 0) return;
    if (MODE == 2) {
        unsafeAtomicAdd(m + (size_t)cur * F + f, acc[0]);
    } else {
        float* mp = m + (size_t)cur * KCH * F + f;
        #pragma unroll
        for (int a = 0; a < KCH; ++a) unsafeAtomicAdd(mp + a * F, acc[a]);
    }
}

template<int MODE>
__device__ __forceinline__ void edge_compute(uint4 gA, uint2 gB, uint4 xav, ushort x8v,
                                             const h2* __restrict__ rwh,
                                             float* __restrict__ acc, int& cur,
                                             float* __restrict__ m, int f) {
    constexpr int NACC = (MODE == 2) ? 1 : KCH;
    int dst = (int)(gA.y >> 16);
    if (dst != cur) {
        flush_acc<MODE>(m, cur, f, acc);
        cur = dst;
        #pragma unroll
        for (int a = 0; a < NACC; ++a) acc[a] = 0.f;
    }

    float2 uxy = unpack2(gA.x);
    float ux = uxy.x, uy = uxy.y;
    float uz = h2f((ushort)(gA.y & 0xFFFFu));
    h2 rc01 = as_h2(gA.z), rc23 = as_h2(gA.w), rc45 = as_h2(gB.x), rc67 = as_h2(gB.y);

    float g0 = fdot2f(rc67, rwh[3],  fdot2f(rc45, rwh[2],  fdot2f(rc23, rwh[1],  fdot2f(rc01, rwh[0], 0.f))));
    float g1 = fdot2f(rc67, rwh[7],  fdot2f(rc45, rwh[6],  fdot2f(rc23, rwh[5],  fdot2f(rc01, rwh[4], 0.f))));
    float g2 = fdot2f(rc67, rwh[11], fdot2f(rc45, rwh[10], fdot2f(rc23, rwh[9],  fdot2f(rc01, rwh[8], 0.f))));

    if (MODE == 0) {
        float xe0 = h2f(x8v);
        float s2 = S3 * g2;
        acc[0] = fmaf(xe0, g0, acc[0]);
        acc[1] = fmaf(xe0, uy * g1, acc[1]);
        acc[2] = fmaf(xe0, uz * g1, acc[2]);
        acc[3] = fmaf(xe0, ux * g1, acc[3]);
        acc[4] = fmaf(xe0, s2 * ux * uy, acc[4]);
        acc[5] = fmaf(xe0, s2 * uy * uz, acc[5]);
        acc[6] = fmaf(xe0, fmaf(1.5f * uz, uz, -0.5f) * g2, acc[6]);
        acc[7] = fmaf(xe0, s2 * ux * uz, acc[7]);
        acc[8] = fmaf(xe0, 0.5f * s2 * (ux * ux - uy * uy), acc[8]);
    } else {
        float xe[9];
        {
            float2 p;
            p = unpack2(xav.x); xe[0] = p.x; xe[1] = p.y;
            p = unpack2(xav.y); xe[2] = p.x; xe[3] = p.y;
            p = unpack2(xav.z); xe[4] = p.x; xe[5] = p.y;
            p = unpack2(xav.w); xe[6] = p.x; xe[7] = p.y;
            xe[8] = h2f(x8v);
        }
        if (MODE == 2) {
            float dot1 = uy * xe[1];
            dot1 = fmaf(uz, xe[2], dot1);
            dot1 = fmaf(ux, xe[3], dot1);
            float Y4 = S3 * ux * uy, Y5 = S3 * uy * uz, Y7 = S3 * ux * uz;
            float Y6 = fmaf(1.5f * uz, uz, -0.5f);
            float Y8 = 0.5f * S3 * (ux * ux - uy * uy);
            float dot2 = Y4 * xe[4];
            dot2 = fmaf(Y5, xe[5], dot2);
            dot2 = fmaf(Y6, xe[6], dot2);
            dot2 = fmaf(Y7, xe[7], dot2);
            dot2 = fmaf(Y8, xe[8], dot2);
            acc[0] = fmaf(g0, xe[0], acc[0]);
            acc[0] = fmaf(g1, dot1, acc[0]);
            acc[0] = fmaf(g2, dot2, acc[0]);
        } else {
            float s2 = S3 * g2;
            float w[9];
            w[0] = g0;
            w[1] = uy * g1; w[2] = uz * g1; w[3] = ux * g1;
            w[4] = s2 * ux * uy;
            w[5] = s2 * uy * uz;
            w[6] = fmaf(1.5f * uz, uz, -0.5f) * g2;
            w[7] = s2 * ux * uz;
            w[8] = 0.5f * s2 * (ux * ux - uy * uy);

            float d0v = xe[0]*w[0], d1v = xe[1]*w[1], d2v = xe[2]*w[2], d3v = xe[3]*w[3];
            float d4v = xe[4]*w[4], d5v = xe[5]*w[5], d6v = xe[6]*w[6], d7v = xe[7]*w[7];
            float d8v = xe[8]*w[8];

            acc[0] += d0v + C13 * (d1v + d2v + d3v) + C15 * (d4v + d5v + d6v + d7v + d8v);
            #define T(a, b) (xe[a] * w[b] + xe[b] * w[a])
            acc[1] += T(0,1) - C15 * T(1,6) - S35 * T(1,8) + S35 * T(2,5) + S35 * T(3,4);
            acc[2] += T(0,2) + S35 * T(1,5) + C25 * T(2,6) + S35 * T(3,7);
            acc[3] += T(0,3) + S35 * T(1,4) + S35 * T(2,7) - C15 * T(3,6) + S35 * T(3,8);
            acc[4] += T(0,4) + IS3 * T(1,3) - C27 * T(4,6) + S37 * T(5,7);
            acc[5] += T(0,5) + IS3 * T(1,2) + S37 * T(4,7) + C17 * T(5,6) - S37 * T(5,8);
            acc[6] += T(0,6) - C13 * d1v + C23 * d2v - C13 * d3v
                    - C27 * d4v + C17 * d5v + C27 * d6v + C17 * d7v - C27 * d8v;
            acc[7] += T(0,7) + IS3 * T(2,3) + S37 * T(4,5) + C17 * T(6,7) + S37 * T(7,8);
            acc[8] += T(0,8) - IS3 * d1v + IS3 * d3v - S37 * d5v + S37 * d7v - C27 * T(6,8);
            #undef T
        }
    }
}

// Strip-parallel segmented reduction, unroll-4 with statically-indexed rings.
// XCD-chunked block swizzle: consecutive strips (shared boundary nodes, contiguous
// geo streams) land on the same XCD's L2. NBLK%8==0 -> bijective.
template<int MODE>   // 0=FIRST(x0h), 1=MID(full Gaunt), 2=LAST(y0 only)
__global__ __launch_bounds__(256) void gather_kernel(const uint4* __restrict__ geoA,
                                                     const uint2* __restrict__ geoB,
                                                     const ushort* __restrict__ njA,
                                                     const ushort* __restrict__ x0h,
                                                     const uint4* __restrict__ xhA,
                                                     const ushort* __restrict__ xhB,
                                                     const float* __restrict__ rw_iter,
                                                     const int* __restrict__ neptr,
                                                     float* __restrict__ m) {
    int lane = threadIdx.x & 63;
    int wid  = threadIdx.x >> 6;
    int half = lane >> 5;
    int f    = lane & 31;
    int lb   = (blockIdx.x & 7) * (NBLK / 8) + (blockIdx.x >> 3);  // XCD-chunked
    int h    = lb * 8 + wid * 2 + half;

    float rwf[24];
    #pragma unroll
    for (int lbq = 0; lbq < 24; ++lbq) rwf[lbq] = rw_iter[lbq * F + f];
    if (MODE == 2) {
        #pragma unroll
        for (int lbq = 8; lbq < 16; ++lbq) rwf[lbq] *= C13;
        #pragma unroll
        for (int lbq = 16; lbq < 24; ++lbq) rwf[lbq] *= C15;
    }
    h2 rwh[12];
    #pragma unroll
    for (int q = 0; q < 12; ++q) {
        h2 v; v.x = (_Float16)rwf[2 * q]; v.y = (_Float16)rwf[2 * q + 1];
        rwh[q] = v;
    }

    int NEl = neptr[0];
    int per = (NEl + NHALF - 1) / NHALF;
    int s = h * per;
    int e = min(s + per, NEl);
    if (s >= e) return;

    constexpr int NACC = (MODE == 2) ? 1 : KCH;
    float acc[NACC];
    #pragma unroll
    for (int a = 0; a < NACC; ++a) acc[a] = 0.f;
    int cur = -1;

    // prologue (pad-safe unclamped reads)
    uint4 ga[4]; uint2 gb[4]; int njr[4];
    uint4 xa[2] = {}; ushort x80[2];
    #pragma unroll
    for (int p = 0; p < 4; ++p) {
        ga[p] = geoA[s + p];
        gb[p] = geoB[s + p];
        njr[p] = (int)njA[s + p + 2];
    }
    {
        int nj0 = (int)njA[s], nj1 = (int)njA[s + 1];
        if (MODE == 0) {
            x80[0] = x0h[nj0 * F + f];
            x80[1] = x0h[nj1 * F + f];
        } else {
            xa[0] = xhA[nj0 * F + f]; x80[0] = xhB[nj0 * F + f];
            xa[1] = xhA[nj1 * F + f]; x80[1] = xhB[nj1 * F + f];
        }
    }

    int t = s;
    while (t + 4 <= e) {
        #pragma unroll
        for (int p = 0; p < 4; ++p) {
            int x = t + p;
            uint4 gAv = ga[p]; uint2 gBv = gb[p];
            ga[p] = geoA[x + 4];
            gb[p] = geoB[x + 4];
            uint4 xav = xa[p & 1];
            ushort x8v = x80[p & 1];
            int njv = njr[p];
            if (MODE == 0) {
                x80[p & 1] = x0h[njv * F + f];
            } else {
                xa[p & 1] = xhA[njv * F + f];
                x80[p & 1] = xhB[njv * F + f];
            }
            njr[p] = (int)njA[x + 6];
            edge_compute<MODE>(gAv, gBv, xav, x8v, rwh, acc, cur, m, f);
        }
        t += 4;
    }
    for (; t < e; ++t) {
        uint4 gAv = geoA[t]; uint2 gBv = geoB[t];
        int njv = (int)njA[t];
        uint4 xav = {}; ushort x8v;
        if (MODE == 0) {
            x8v = x0h[njv * F + f];
        } else {
            xav = xhA[njv * F + f];
            x8v = xhB[njv * F + f];
        }
        edge_compute<MODE>(gAv, gBv, xav, x8v, rwh, acc, cur, m, f);
    }
    flush_acc<MODE>(m, cur, f, acc);
}

// thread = (node, f). State in fp16 (xhA/xhB) + f32 master of k=0 row (x0).
__global__ __launch_bounds__(256) void node_full(float* __restrict__ x0,
                                                 const float* __restrict__ m,
                                                 uint4* __restrict__ xhA,
                                                 ushort* __restrict__ xhB,
                                                 const float* __restrict__ w1,
                                                 const float* __restrict__ b1,
                                                 const float* __restrict__ w2,
                                                 const float* __restrict__ b2) {
    __shared__ float tile[8][KCH][F];
    int nl = threadIdx.x >> 5, f = threadIdx.x & 31;
    int n = blockIdx.x * 8 + nl;

    float w1c[F];
    #pragma unroll
    for (int fi = 0; fi < F; ++fi) w1c[fi] = w1[fi * F + f];

    float xk[KCH];
    {
        uint4 ua = xhA[n * F + f];
        ushort ub = xhB[n * F + f];
        float2 p;
        p = unpack2(ua.x); xk[0] = p.x; xk[1] = p.y;
        p = unpack2(ua.y); xk[2] = p.x; xk[3] = p.y;
        p = unpack2(ua.z); xk[4] = p.x; xk[5] = p.y;
        p = unpack2(ua.w); xk[6] = p.x; xk[7] = p.y;
        xk[8] = h2f(ub);
    }
    xk[0] = x0[n * F + f];

    #pragma unroll
    for (int k = 0; k < KCH; ++k)
        tile[nl][k][f] = xk[k] + m[((size_t)n * KCH + k) * F + f];
    __syncthreads();

    float o1[KCH];
    #pragma unroll
    for (int k = 0; k < KCH; ++k) {
        float s = 0.f;
        #pragma unroll
        for (int fi = 0; fi < F; ++fi) s = fmaf(tile[nl][k][fi], w1c[fi], s);
        o1[k] = s;
    }
    o1[0] += b1[f];
    float gate = 1.0f / (1.0f + expf(-o1[0]));
    __syncthreads();
    #pragma unroll
    for (int k = 0; k < KCH; ++k) tile[nl][k][f] = o1[k] * gate;
    __syncthreads();

    float w2c[F];
    #pragma unroll
    for (int fi = 0; fi < F; ++fi) w2c[fi] = w2[fi * F + f];

    float xn[KCH];
    #pragma unroll
    for (int k = 0; k < KCH; ++k) {
        float s = (k == 0) ? b2[f] : 0.f;
        #pragma unroll
        for (int fi = 0; fi < F; ++fi) s = fmaf(tile[nl][k][fi], w2c[fi], s);
        xn[k] = xk[k] + s;
    }

    x0[n * F + f] = xn[0];
    uint4 ua;
    ua.x = pack2(xn[0], xn[1]); ua.y = pack2(xn[2], xn[3]);
    ua.z = pack2(xn[4], xn[5]); ua.w = pack2(xn[6], xn[7]);
    xhA[n * F + f] = ua;
    xhB[n * F + f] = __half_as_ushort(__float2half_rn(xn[8]));
}

__global__ __launch_bounds__(256) void node_last(const float* __restrict__ x0,
                                                 const float* __restrict__ m1,
                                                 const float* __restrict__ w1,
                                                 const float* __restrict__ b1,
                                                 const float* __restrict__ w2,
                                                 const float* __restrict__ b2,
                                                 float* __restrict__ out) {
    __shared__ float tile[8][F];
    int nl = threadIdx.x >> 5, f = threadIdx.x & 31;
    int n = blockIdx.x * 8 + nl;

    float w1c[F];
    #pragma unroll
    for (int fi = 0; fi < F; ++fi) w1c[fi] = w1[fi * F + f];

    float xv = x0[n * F + f];
    tile[nl][f] = xv + m1[(size_t)n * F + f];
    __syncthreads();
    float s = 0.f;
    #pragma unroll
    for (int fi = 0; fi < F; ++fi) s = fmaf(tile[nl][fi], w1c[fi], s);
    s += b1[f];
    float gate = 1.0f / (1.0f + expf(-s));
    float h2v = s * gate;
    __syncthreads();
    tile[nl][f] = h2v;
    __syncthreads();
    float w2c[F];
    #pragma unroll
    for (int fi = 0; fi < F; ++fi) w2c[fi] = w2[fi * F + f];
    float o = b2[f];
    #pragma unroll
    for (int fi = 0; fi < F; ++fi) o = fmaf(tile[nl][fi], w2c[fi], o);
    out[(size_t)n * F + f] = xv + o;
}

extern "C" void kernel_launch(void* const* d_in, const int* in_sizes, int n_in,
                              void* d_out, int out_size, void* d_ws, size_t ws_size,
                              hipStream_t stream) {
    (void)in_sizes; (void)n_in; (void)out_size; (void)ws_size;
    const float* dr    = (const float*)d_in[0];
    const float* embed = (const float*)d_in[1];
    const float* rad_w = (const float*)d_in[2];
    const float* d1w   = (const float*)d_in[3];
    const float* d1b   = (const float*)d_in[4];
    const float* d2w   = (const float*)d_in[5];
    const float* d2b   = (const float*)d_in[6];
    const int*   Z     = (const int*)d_in[7];
    const int*   nidx  = (const int*)d_in[8];
    const int* idx_i = nidx;
    const int* idx_j = nidx + NE;

    // workspace layout (16B-aligned head); geo/nj streams padded by 8 entries
    uint4* xhA  = (uint4*)d_ws;                                 // NN*F uint4
    float* m    = (float*)(xhA + (size_t)NN * F);               // NN*9*F f32
    float* x0   = m + (size_t)NN * KCH * F;                     // NN*F f32
    ushort* x0h = (ushort*)(x0 + (size_t)NN * F);               // NN*F u16
    ushort* xhB = x0h + (size_t)NN * F;                         // NN*F u16
    uint4* geoA = (uint4*)(xhB + (size_t)NN * F);               // (NE+8) uint4
    uint2* geoB = (uint2*)(geoA + (size_t)NE + 8);              // (NE+8) uint2
    ushort* njA = (ushort*)(geoB + (size_t)NE + 8);             // (NE+8) u16
    int* offs = (int*)(njA + (size_t)NE + 8);                   // NN+1
    int* head = offs + (NN + 1);
    int* cnt  = head + NN;
    float* outp = (float*)d_out;

    size_t MB_full = (size_t)NN * KCH * F * sizeof(float);
    size_t MB_last = (size_t)NN * F * sizeof(float);

    hipMemsetAsync(cnt, 0, NN * sizeof(int), stream);
    hist_kernel<<<(NE + 255) / 256, 256, 0, stream>>>(idx_i, idx_j, dr, cnt);
    scan_kernel<<<1, SCAN_T, 0, stream>>>(cnt, offs, head);
    pad_zero<<<1, 64, 0, stream>>>(offs + NN, geoA, geoB, njA);
    fill_kernel<<<(NE + 255) / 256, 256, 0, stream>>>(idx_i, idx_j, dr, head, geoA, geoB, njA);

    init_x<<<NN * F / 256, 256, 0, stream>>>(embed, Z, x0, x0h, xhA, xhB);

    const int* neptr = offs + NN;
    for (int i = 0; i < 3; ++i) {
        const float* rwi = rad_w + (size_t)i * 3 * 8 * F;
        const float* w1 = d1w + (size_t)i * F * F;
        const float* b1 = d1b + (size_t)i * F;
        const float* w2 = d2w + (size_t)i * F * F;
        const float* b2 = d2b + (size_t)i * F;
        if (i == 0) {
            hipMemsetAsync(m, 0, MB_full, stream);
            gather_kernel<0><<<NBLK, 256, 0, stream>>>(geoA, geoB, njA, x0h, xhA, xhB, rwi, neptr, m);
            node_full<<<NN / 8, 256, 0, stream>>>(x0, m, xhA, xhB, w1, b1, w2, b2);
        } else if (i == 1) {
            hipMemsetAsync(m, 0, MB_full, stream);
            gather_kernel<1><<<NBLK, 256, 0, stream>>>(geoA, geoB, njA, x0h, xhA, xhB, rwi, neptr, m);
            node_full<<<NN / 8, 256, 0, stream>>>(x0, m, xhA, xhB, w1, b1, w2, b2);
        } else {
            hipMemsetAsync(m, 0, MB_last, stream);
            gather_kernel<2><<<NBLK, 256, 0, stream>>>(geoA, geoB, njA, x0h, xhA, xhB, rwi, neptr, m);
            node_last<<<NN / 8, 256, 0, stream>>>(x0, m, w1, b1, w2, b2, outp);
        }
    }
}